// Round 7
// baseline (183.238 us; speedup 1.0000x reference)
//
#include <hip/hip_runtime.h>

// 100x100 sliding mean over x[32][1][1124][1124] f32 -> out[32][1][1025][1025] f32.
// Two passes. H: horizontal 100-sum -> T (f16, stride 1032) in d_ws, computed
//   entirely in registers (no LDS): each thread slides a 32-output chunk.
// V: vertical 100-sum + 1e-4 scale, explicit load batching for MLP, NT stores.
// Cache plan: T (74 MB) cached so pass V reads mostly hit Infinity Cache; out
// stores are nontemporal so they don't evict T.

#define H_IN    1124
#define W_IN    1124
#define KWIN    100
#define W_OUT   1025
#define H_OUT   1025
#define TSTR    1032   // T row stride in halves (2064 B -> rows 16B-aligned)
#define NBANDS  16
#define BANDR   65     // 16*65 = 1040 >= 1025

typedef float    f32x4 __attribute__((ext_vector_type(4)));
typedef _Float16 f16x4 __attribute__((ext_vector_type(4)));
typedef _Float16 f16x8 __attribute__((ext_vector_type(8)));

// ---------------- Pass H: register-sliding, LDS-free ------------------------
// block 256 = 8 rows x 32 chunks; thread = 32 consecutive outputs of one row.
__global__ __launch_bounds__(256) void hslide_kernel(
    const float* __restrict__ x,     // [g][1124][1124]
    _Float16* __restrict__ T)        // [g][1124][TSTR]
{
    const int tid   = threadIdx.x;
    const int chunk = tid & 31;          // 0..31 -> output cols chunk*32..+31
    const int lr    = tid >> 5;          // 0..7
    const int row   = blockIdx.x * 8 + lr;
    if (row >= H_IN) return;
    const int b     = blockIdx.y;

    const f32x4* xr = (const f32x4*)(x + ((size_t)b * H_IN + row) * W_IN)
                    + (size_t)chunk * 8;

    f32x4 lo[8], hi[8];
    #pragma unroll
    for (int j = 0; j < 8; ++j) lo[j] = xr[j];          // floats c0..c0+31
    #pragma unroll
    for (int j = 0; j < 8; ++j) hi[j] = xr[25 + j];     // floats c0+100..c0+131

    // initial 100-tap sum: floats c0..c0+99 = f4[0..24]; 4 independent chains
    f32x4 acc = lo[0];
    #pragma unroll
    for (int j = 1; j < 8; ++j) acc += lo[j];
    #pragma unroll
    for (int j = 8; j < 25; ++j) acc += xr[j];
    float s = (acc.x + acc.y) + (acc.z + acc.w);

    // slide 31 times, packing f16 outputs on the fly
    f16x8 pk[4];
    pk[0][0] = (_Float16)s;
    #pragma unroll
    for (int k = 0; k < 31; ++k) {
        s += hi[k >> 2][k & 3] - lo[k >> 2][k & 3];
        pk[(k + 1) >> 3][(k + 1) & 7] = (_Float16)s;
    }

    _Float16* trow = T + ((size_t)b * H_IN + row) * TSTR + chunk * 32;
    #pragma unroll
    for (int g2 = 0; g2 < 4; ++g2)
        *((f16x8*)trow + g2) = pk[g2];                  // 4 x 16B, 16B-aligned

    if (chunk == 31) {                                  // output col 1024
        float s33 = s + hi[7].w - lo[7].w;              // + x[1123] - x[1023]
        trow[32] = (_Float16)s33;
    }
}

// ---------------- Pass V: 4 f16 cols/thread, batched loads, NT stores -------
// grid (2 col-tiles, NBANDS, g), block 128. tile1/tid127 also owns col 1024
// (loaded as a vector; pad cols 1025..1027 hold finite 0xAA-pattern garbage
// that is accumulated into lanes we never store).
__global__ __launch_bounds__(128) void vslide_kernel(
    const _Float16* __restrict__ T,  // [g][1124][TSTR]
    float* __restrict__ out)         // [g][1025][1025]
{
    const int tid  = threadIdx.x;
    const int tile = blockIdx.x;
    const int band = blockIdx.y;
    const int b    = blockIdx.z;
    const int r0   = band * BANDR;
    const int nr   = min(BANDR, H_OUT - r0);

    const int w0 = tile * 512 + tid * 4;
    const _Float16* base = T + ((size_t)b * H_IN + r0) * TSTR + w0;
    const bool xtra = (tile == 1) && (tid == 127);      // w0 == 1020
    const float scale = 1.0f / (float)(KWIN * KWIN);

    float s0 = 0.f, s1 = 0.f, s2 = 0.f, s3 = 0.f, s8 = 0.f;

    // ---- prologue: rows r0..r0+99 in batches of 8 independent loads ----
    {
        const _Float16* p = base;
        #pragma unroll 2
        for (int cg = 0; cg < 12; ++cg) {               // 96 rows
            f16x4 v[8];
            #pragma unroll
            for (int j = 0; j < 8; ++j)
                v[j] = *(const f16x4*)(p + (size_t)j * TSTR);
            f16x4 vc[8];
            if (xtra) {
                #pragma unroll
                for (int j = 0; j < 8; ++j)
                    vc[j] = *(const f16x4*)(p + (size_t)j * TSTR + 4);
            }
            #pragma unroll
            for (int j = 0; j < 8; ++j) {
                s0 += (float)v[j][0]; s1 += (float)v[j][1];
                s2 += (float)v[j][2]; s3 += (float)v[j][3];
            }
            if (xtra) {
                #pragma unroll
                for (int j = 0; j < 8; ++j) s8 += (float)vc[j][0];
            }
            p += (size_t)8 * TSTR;
        }
        {                                               // 4 remaining rows
            f16x4 v[4];
            #pragma unroll
            for (int j = 0; j < 4; ++j)
                v[j] = *(const f16x4*)(p + (size_t)j * TSTR);
            #pragma unroll
            for (int j = 0; j < 4; ++j) {
                s0 += (float)v[j][0]; s1 += (float)v[j][1];
                s2 += (float)v[j][2]; s3 += (float)v[j][3];
            }
            if (xtra) {
                #pragma unroll
                for (int j = 0; j < 4; ++j)
                    s8 += (float)*(p + (size_t)j * TSTR + 4);
            }
        }
    }

    float* q = out + ((size_t)b * H_OUT + r0) * W_OUT + w0;
    __builtin_nontemporal_store(s0 * scale, q + 0);
    __builtin_nontemporal_store(s1 * scale, q + 1);
    __builtin_nontemporal_store(s2 * scale, q + 2);
    __builtin_nontemporal_store(s3 * scale, q + 3);
    if (xtra) __builtin_nontemporal_store(s8 * scale, q + 4);   // col 1024
    q += W_OUT;

    // ---- steady: add row +100, sub row, emit; 4-row groups, batched loads --
    const _Float16* pa = base + (size_t)KWIN * TSTR;
    const _Float16* pd = base;
    const int steps = nr - 1;
    int i = 0;
    for (; i + 4 <= steps; i += 4) {
        f16x4 a[4], d[4], ac[4], dc[4];
        #pragma unroll
        for (int j = 0; j < 4; ++j) {
            a[j] = *(const f16x4*)(pa + (size_t)j * TSTR);
            d[j] = *(const f16x4*)(pd + (size_t)j * TSTR);
        }
        if (xtra) {
            #pragma unroll
            for (int j = 0; j < 4; ++j) {
                ac[j] = *(const f16x4*)(pa + (size_t)j * TSTR + 4);
                dc[j] = *(const f16x4*)(pd + (size_t)j * TSTR + 4);
            }
        }
        #pragma unroll
        for (int j = 0; j < 4; ++j) {
            s0 += (float)a[j][0] - (float)d[j][0];
            s1 += (float)a[j][1] - (float)d[j][1];
            s2 += (float)a[j][2] - (float)d[j][2];
            s3 += (float)a[j][3] - (float)d[j][3];
            __builtin_nontemporal_store(s0 * scale, q + 0);
            __builtin_nontemporal_store(s1 * scale, q + 1);
            __builtin_nontemporal_store(s2 * scale, q + 2);
            __builtin_nontemporal_store(s3 * scale, q + 3);
            if (xtra) {
                s8 += (float)ac[j][0] - (float)dc[j][0];
                __builtin_nontemporal_store(s8 * scale, q + 4);
            }
            q += W_OUT;
        }
        pa += (size_t)4 * TSTR;
        pd += (size_t)4 * TSTR;
    }
    for (; i < steps; ++i) {
        f16x4 a = *(const f16x4*)pa, d = *(const f16x4*)pd;
        s0 += (float)a[0] - (float)d[0];
        s1 += (float)a[1] - (float)d[1];
        s2 += (float)a[2] - (float)d[2];
        s3 += (float)a[3] - (float)d[3];
        __builtin_nontemporal_store(s0 * scale, q + 0);
        __builtin_nontemporal_store(s1 * scale, q + 1);
        __builtin_nontemporal_store(s2 * scale, q + 2);
        __builtin_nontemporal_store(s3 * scale, q + 3);
        if (xtra) {
            s8 += (float)*(pa + 4) - (float)*(pd + 4);
            __builtin_nontemporal_store(s8 * scale, q + 4);
        }
        pa += TSTR; pd += TSTR; q += W_OUT;
    }
}

extern "C" void kernel_launch(void* const* d_in, const int* in_sizes, int n_in,
                              void* d_out, int out_size, void* d_ws, size_t ws_size,
                              hipStream_t stream) {
    const float* x = (const float*)d_in[0];
    float* out     = (float*)d_out;
    _Float16* ws   = (_Float16*)d_ws;

    const int B = 32;
    const size_t perBatchT = (size_t)H_IN * TSTR * sizeof(_Float16);  // ~2.32 MB

    int G = (int)(ws_size / perBatchT);
    if (G > B) G = B;
    if (G < 1) G = 1;

    for (int b0 = 0; b0 < B; b0 += G) {
        const int g = (B - b0 < G) ? (B - b0) : G;

        dim3 hgrid((H_IN + 7) / 8, g);
        hslide_kernel<<<hgrid, 256, 0, stream>>>(
            x + (size_t)b0 * H_IN * W_IN, ws);

        dim3 vgrid(2, NBANDS, g);
        vslide_kernel<<<vgrid, 128, 0, stream>>>(
            ws, out + (size_t)b0 * H_OUT * W_OUT);
    }
}

// Round 8
// 135.128 us; speedup vs baseline: 1.3560x; 1.3560x over previous
//
#include <hip/hip_runtime.h>

// 100x100 sliding mean over x[32][1][1124][1124] f32 -> out[32][1][1025][1025] f32.
// Pass H (LDS form, R6): horizontal 100-sum -> T (f16, stride 1032) in d_ws.
// Pass V: vertical 100-sum + 1e-4 scale. Strided column ownership (thread owns
// cols {c0+tid, c0+tid+256}) so every scalar f32 NT store is wave-contiguous
// (full 64B lines) and every scalar f16 load is 128B-contiguous per wave.
// Cache plan: x loads NT (read-once), T cached (74 MB, L3-resident), out NT.

#define H_IN    1124
#define W_IN    1124
#define KWIN    100
#define W_OUT   1025
#define H_OUT   1025
#define TSTR    1032   // T row stride in halves (2064 B -> rows 16B-aligned)
#define NBANDS  16
#define BANDR   65     // 16*65 = 1040 >= 1025

typedef float    f32x4 __attribute__((ext_vector_type(4)));
typedef _Float16 f16x8 __attribute__((ext_vector_type(8)));

struct alignas(8) h4 { _Float16 a, b, c, d; };

// ---------------- Pass H: one block per input row, f16 T output -------------
__global__ __launch_bounds__(256) void hslide_kernel(
    const float* __restrict__ x,     // [g*1124][1124]
    _Float16* __restrict__ T)        // [g*1124][TSTR]
{
    __shared__ float srow[W_IN];     // 1124 floats
    __shared__ float ps[282];        // ps[j] = srow[4j] + .. + srow[4j+3]

    const int row = blockIdx.x;
    const int tid = threadIdx.x;
    const f32x4* xr4 = (const f32x4*)(x + (size_t)row * W_IN);

    for (int i = tid; i < 281; i += 256)
        ((f32x4*)srow)[i] = __builtin_nontemporal_load(xr4 + i);
    __syncthreads();

    float4 lo = ((const float4*)srow)[tid];
    ps[tid] = lo.x + lo.y + lo.z + lo.w;
    if (tid < 25) {
        float4 v = ((const float4*)srow)[256 + tid];
        ps[256 + tid] = v.x + v.y + v.z + v.w;
    }
    __syncthreads();

    _Float16* trow = T + (size_t)row * TSTR;
    {
        const int w0 = tid * 4;
        float s = 0.f;
        #pragma unroll
        for (int j = 0; j < 25; ++j) s += ps[tid + j];   // taps w0..w0+99
        float4 hi = ((const float4*)srow)[tid + 25];     // srow[w0+100..w0+103]
        float s1 = s  + hi.x - lo.x;
        float s2 = s1 + hi.y - lo.y;
        float s3 = s2 + hi.z - lo.z;
        *(h4*)(trow + w0) = h4{ (_Float16)s, (_Float16)s1,
                                (_Float16)s2, (_Float16)s3 };
        if (tid == 255) {
            float t = 0.f;
            #pragma unroll
            for (int j = 0; j < 25; ++j) t += ps[256 + j];      // taps 1024..1123
            *(h4*)(trow + 1024) = h4{ (_Float16)t, (_Float16)0.f,
                                      (_Float16)0.f, (_Float16)0.f };
            *(h4*)(trow + 1028) = h4{ (_Float16)0.f, (_Float16)0.f,
                                      (_Float16)0.f, (_Float16)0.f };
        }
    }
}

// ---------------- Pass V: strided cols, scalar loads/stores, deep MLP -------
// grid (2 tiles, NBANDS, g), block 256. Thread owns cols c0+tid and c0+tid+256.
// tile 1, tid 0 additionally owns col 1024.
__global__ __launch_bounds__(256) void vslide_kernel(
    const _Float16* __restrict__ T,  // [g*1124][TSTR]
    float* __restrict__ out)         // [g][1025][1025]
{
    const int tid  = threadIdx.x;
    const int tile = blockIdx.x;
    const int band = blockIdx.y;
    const int b    = blockIdx.z;
    const int r0   = band * BANDR;
    const int nr   = min(BANDR, H_OUT - r0);
    if (nr <= 0) return;

    const int c0 = tile * 512;
    const bool xtra = (tile == 1) && (tid == 0);
    const float scale = 1.0f / (float)(KWIN * KWIN);

    const _Float16* baseA = T + ((size_t)b * H_IN + r0) * TSTR + c0 + tid;
    const _Float16* baseB = baseA + 256;
    const _Float16* baseC = T + ((size_t)b * H_IN + r0) * TSTR + 1024;

    float sA = 0.f, sB = 0.f, sC = 0.f;

    // ---- prologue: rows r0..r0+99, batches of 8 independent rows ----
    {
        const _Float16* pA = baseA;
        const _Float16* pB = baseB;
        const _Float16* pC = baseC;
        for (int cg = 0; cg < 12; ++cg) {          // 96 rows
            float a[8], c[8];
            #pragma unroll
            for (int j = 0; j < 8; ++j) {
                a[j] = (float)pA[(size_t)j * TSTR];
                c[j] = (float)pB[(size_t)j * TSTR];
            }
            #pragma unroll
            for (int j = 0; j < 8; ++j) { sA += a[j]; sB += c[j]; }
            if (xtra) {
                #pragma unroll
                for (int j = 0; j < 8; ++j) sC += (float)pC[(size_t)j * TSTR];
            }
            pA += (size_t)8 * TSTR; pB += (size_t)8 * TSTR; pC += (size_t)8 * TSTR;
        }
        #pragma unroll
        for (int j = 0; j < 4; ++j) {              // 4 remaining rows
            sA += (float)pA[(size_t)j * TSTR];
            sB += (float)pB[(size_t)j * TSTR];
            if (xtra) sC += (float)pC[(size_t)j * TSTR];
        }
    }

    float* qrow = out + ((size_t)b * H_OUT + r0) * W_OUT;
    __builtin_nontemporal_store(sA * scale, qrow + c0 + tid);
    __builtin_nontemporal_store(sB * scale, qrow + c0 + tid + 256);
    if (xtra) __builtin_nontemporal_store(sC * scale, qrow + 1024);
    qrow += W_OUT;

    // ---- steady: add row r0+100+i, sub row r0+i, emit row r0+1+i ----
    const _Float16* aA = baseA + (size_t)KWIN * TSTR;
    const _Float16* aB = baseB + (size_t)KWIN * TSTR;
    const _Float16* aC = baseC + (size_t)KWIN * TSTR;
    const _Float16* dA = baseA;
    const _Float16* dB = baseB;
    const _Float16* dC = baseC;

    const int steps = nr - 1;
    int i = 0;
    for (; i + 8 <= steps; i += 8) {
        float addA[8], addB[8], subA[8], subB[8];
        #pragma unroll
        for (int j = 0; j < 8; ++j) {
            addA[j] = (float)aA[(size_t)j * TSTR];
            addB[j] = (float)aB[(size_t)j * TSTR];
            subA[j] = (float)dA[(size_t)j * TSTR];
            subB[j] = (float)dB[(size_t)j * TSTR];
        }
        float addC[8], subC[8];
        if (xtra) {
            #pragma unroll
            for (int j = 0; j < 8; ++j) {
                addC[j] = (float)aC[(size_t)j * TSTR];
                subC[j] = (float)dC[(size_t)j * TSTR];
            }
        }
        float* q = qrow;
        #pragma unroll
        for (int j = 0; j < 8; ++j) {
            sA += addA[j] - subA[j];
            sB += addB[j] - subB[j];
            __builtin_nontemporal_store(sA * scale, q + c0 + tid);
            __builtin_nontemporal_store(sB * scale, q + c0 + tid + 256);
            if (xtra) {
                sC += addC[j] - subC[j];
                __builtin_nontemporal_store(sC * scale, q + 1024);
            }
            q += W_OUT;
        }
        qrow = q;
        aA += (size_t)8 * TSTR; aB += (size_t)8 * TSTR; aC += (size_t)8 * TSTR;
        dA += (size_t)8 * TSTR; dB += (size_t)8 * TSTR; dC += (size_t)8 * TSTR;
    }
    for (; i < steps; ++i) {
        sA += (float)aA[0] - (float)dA[0];
        sB += (float)aB[0] - (float)dB[0];
        __builtin_nontemporal_store(sA * scale, qrow + c0 + tid);
        __builtin_nontemporal_store(sB * scale, qrow + c0 + tid + 256);
        if (xtra) {
            sC += (float)aC[0] - (float)dC[0];
            __builtin_nontemporal_store(sC * scale, qrow + 1024);
        }
        aA += TSTR; aB += TSTR; aC += TSTR;
        dA += TSTR; dB += TSTR; dC += TSTR;
        qrow += W_OUT;
    }
}

extern "C" void kernel_launch(void* const* d_in, const int* in_sizes, int n_in,
                              void* d_out, int out_size, void* d_ws, size_t ws_size,
                              hipStream_t stream) {
    const float* x = (const float*)d_in[0];
    float* out     = (float*)d_out;
    _Float16* ws   = (_Float16*)d_ws;

    const int B = 32;
    const size_t perBatchT = (size_t)H_IN * TSTR * sizeof(_Float16);  // ~2.32 MB

    int G = (int)(ws_size / perBatchT);
    if (G > B) G = B;
    if (G < 1) G = 1;

    for (int b0 = 0; b0 < B; b0 += G) {
        const int g = (B - b0 < G) ? (B - b0) : G;

        hslide_kernel<<<g * H_IN, 256, 0, stream>>>(
            x + (size_t)b0 * H_IN * W_IN, ws);

        dim3 vgrid(2, NBANDS, g);
        vslide_kernel<<<vgrid, 256, 0, stream>>>(
            ws, out + (size_t)b0 * H_OUT * W_OUT);
    }
}

// Round 9
// 115.189 us; speedup vs baseline: 1.5908x; 1.1731x over previous
//
#include <hip/hip_runtime.h>

// 100x100 sliding mean over x[32][1][1124][1124] f32 -> out[32][1][1025][1025] f32.
// Pass H: horizontal 100-sum -> T (f16, stride 1032) in d_ws. Three-level LDS
//   partials (srow -> ps sums-of-4 -> qs sliding sums-of-16) make the 100-tap
//   sum cost 7 uniform ds_read_b32 per thread instead of 25 (LDS-issue was the
//   hslide bottleneck: ~42us of ds traffic vs 37.5us HBM floor).
// Pass V: vertical 100-sum + 1e-4 scale. R5-measured-best shape: 13 bands
//   (lowest halo amp), f16x8-wide cached T loads replaced by f16x4 at 128thr x
//   2 strips, batch-4 steady loads for MLP, nontemporal out stores.

#define H_IN    1124
#define W_IN    1124
#define KWIN    100
#define W_OUT   1025
#define H_OUT   1025
#define TSTR    1032   // T row stride in halves (2064 B -> rows 16B-aligned)
#define NBANDS  13
#define BANDR   79     // 13*79 = 1027 >= 1025

typedef float    f32x4 __attribute__((ext_vector_type(4)));
typedef _Float16 f16x4 __attribute__((ext_vector_type(4)));

struct alignas(8) h4 { _Float16 a, b, c, d; };

// ---------------- Pass H: one block per input row, f16 T output -------------
__global__ __launch_bounds__(256) void hslide_kernel(
    const float* __restrict__ x,     // [g*1124][1124]
    _Float16* __restrict__ T)        // [g*1124][TSTR]
{
    __shared__ float srow[W_IN];     // 1124 floats
    __shared__ float ps[284];        // ps[j] = srow[4j..4j+3], j < 281
    __shared__ float qs[280];        // qs[j] = ps[j]+ps[j+1]+ps[j+2]+ps[j+3], j < 278

    const int row = blockIdx.x;
    const int tid = threadIdx.x;
    const f32x4* xr4 = (const f32x4*)(x + (size_t)row * W_IN);

    for (int i = tid; i < 281; i += 256)
        ((f32x4*)srow)[i] = __builtin_nontemporal_load(xr4 + i);
    __syncthreads();

    // level 1: sums of 4
    f32x4 lo = ((const f32x4*)srow)[tid];
    const float myps = lo[0] + lo[1] + lo[2] + lo[3];
    ps[tid] = myps;
    float myps2 = 0.f;
    if (tid < 25) {
        f32x4 v = ((const f32x4*)srow)[256 + tid];
        myps2 = v[0] + v[1] + v[2] + v[3];
        ps[256 + tid] = myps2;
    }
    __syncthreads();

    // level 2: sliding sums of 16 (4 consecutive ps)
    qs[tid] = myps + ps[tid + 1] + ps[tid + 2] + ps[tid + 3];          // j = tid < 278
    if (tid < 22)
        qs[256 + tid] = myps2 + ps[257 + tid] + ps[258 + tid] + ps[259 + tid];
    __syncthreads();

    // 100-tap sums + slide, outputs w0 = 4*tid .. +3
    _Float16* trow = T + (size_t)row * TSTR;
    {
        float s = ps[tid + 24];
        #pragma unroll
        for (int i = 0; i < 6; ++i) s += qs[tid + 4 * i];   // ps[tid..tid+23]
        f32x4 hi = ((const f32x4*)srow)[tid + 25];          // srow[4t+100..4t+103]
        float s1 = s  + hi[0] - lo[0];
        float s2 = s1 + hi[1] - lo[1];
        float s3 = s2 + hi[2] - lo[2];
        *(h4*)(trow + 4 * tid) = h4{ (_Float16)s, (_Float16)s1,
                                     (_Float16)s2, (_Float16)s3 };
        if (tid == 255) {                                   // col 1024
            float t = ps[280];
            #pragma unroll
            for (int i = 0; i < 6; ++i) t += qs[256 + 4 * i];
            *(h4*)(trow + 1024) = h4{ (_Float16)t, (_Float16)0.f,
                                      (_Float16)0.f, (_Float16)0.f };
            *(h4*)(trow + 1028) = h4{ (_Float16)0.f, (_Float16)0.f,
                                      (_Float16)0.f, (_Float16)0.f };
        }
    }
}

// ---------------- Pass V: f16x4 cached loads, batch-4 steady, NT stores -----
// grid (2 strips, NBANDS, g), block 128. Thread owns cols strip*512+4*tid..+3;
// strip 1 / tid 127 additionally owns col 1024 (via the f16x4 at +4: pad cols
// 1025..1027 are zeros written by hslide).
__global__ __launch_bounds__(128) void vslide_kernel(
    const _Float16* __restrict__ T,  // [g*1124][TSTR]
    float* __restrict__ out)         // [g][1025][1025]
{
    const int tid   = threadIdx.x;
    const int strip = blockIdx.x;
    const int band  = blockIdx.y;
    const int b     = blockIdx.z;
    const int r0    = band * BANDR;
    const int nr    = min(BANDR, H_OUT - r0);
    if (nr <= 0) return;

    const int w0 = strip * 512 + tid * 4;
    const bool xtra = (strip == 1) && (tid == 127);     // w0 == 1020
    const float scale = 1.0f / (float)(KWIN * KWIN);

    const _Float16* base = T + ((size_t)b * H_IN + r0) * TSTR + w0;

    float s0 = 0.f, s1 = 0.f, s2 = 0.f, s3 = 0.f, s8 = 0.f;

    // ---- prologue: rows r0..r0+99, batches of 8 independent 8B loads ----
    {
        const _Float16* p = base;
        for (int cg = 0; cg < 12; ++cg) {               // 96 rows
            f16x4 v[8];
            #pragma unroll
            for (int j = 0; j < 8; ++j)
                v[j] = *(const f16x4*)(p + (size_t)j * TSTR);
            f16x4 vc[8];
            if (xtra) {
                #pragma unroll
                for (int j = 0; j < 8; ++j)
                    vc[j] = *(const f16x4*)(p + (size_t)j * TSTR + 4);
            }
            #pragma unroll
            for (int j = 0; j < 8; ++j) {
                s0 += (float)v[j][0]; s1 += (float)v[j][1];
                s2 += (float)v[j][2]; s3 += (float)v[j][3];
            }
            if (xtra) {
                #pragma unroll
                for (int j = 0; j < 8; ++j) s8 += (float)vc[j][0];
            }
            p += (size_t)8 * TSTR;
        }
        #pragma unroll
        for (int j = 0; j < 4; ++j) {                   // 4 remaining rows
            f16x4 v = *(const f16x4*)(p + (size_t)j * TSTR);
            s0 += (float)v[0]; s1 += (float)v[1];
            s2 += (float)v[2]; s3 += (float)v[3];
            if (xtra) s8 += (float)*(p + (size_t)j * TSTR + 4);
        }
    }

    float* q = out + ((size_t)b * H_OUT + r0) * W_OUT + w0;
    __builtin_nontemporal_store(s0 * scale, q + 0);
    __builtin_nontemporal_store(s1 * scale, q + 1);
    __builtin_nontemporal_store(s2 * scale, q + 2);
    __builtin_nontemporal_store(s3 * scale, q + 3);
    if (xtra) __builtin_nontemporal_store(s8 * scale, q + 4);   // col 1024
    q += W_OUT;

    // ---- steady: batches of 4 steps (8 loads in flight), then remainder ----
    const _Float16* pa = base + (size_t)KWIN * TSTR;
    const _Float16* pd = base;
    const int steps = nr - 1;
    int i = 0;
    for (; i + 4 <= steps; i += 4) {
        f16x4 a[4], d[4];
        #pragma unroll
        for (int j = 0; j < 4; ++j) {
            a[j] = *(const f16x4*)(pa + (size_t)j * TSTR);
            d[j] = *(const f16x4*)(pd + (size_t)j * TSTR);
        }
        f16x4 ac[4], dc[4];
        if (xtra) {
            #pragma unroll
            for (int j = 0; j < 4; ++j) {
                ac[j] = *(const f16x4*)(pa + (size_t)j * TSTR + 4);
                dc[j] = *(const f16x4*)(pd + (size_t)j * TSTR + 4);
            }
        }
        #pragma unroll
        for (int j = 0; j < 4; ++j) {
            s0 += (float)a[j][0] - (float)d[j][0];
            s1 += (float)a[j][1] - (float)d[j][1];
            s2 += (float)a[j][2] - (float)d[j][2];
            s3 += (float)a[j][3] - (float)d[j][3];
            __builtin_nontemporal_store(s0 * scale, q + 0);
            __builtin_nontemporal_store(s1 * scale, q + 1);
            __builtin_nontemporal_store(s2 * scale, q + 2);
            __builtin_nontemporal_store(s3 * scale, q + 3);
            if (xtra) {
                s8 += (float)ac[j][0] - (float)dc[j][0];
                __builtin_nontemporal_store(s8 * scale, q + 4);
            }
            q += W_OUT;
        }
        pa += (size_t)4 * TSTR;
        pd += (size_t)4 * TSTR;
    }
    for (; i < steps; ++i) {
        f16x4 a = *(const f16x4*)pa, d = *(const f16x4*)pd;
        s0 += (float)a[0] - (float)d[0];
        s1 += (float)a[1] - (float)d[1];
        s2 += (float)a[2] - (float)d[2];
        s3 += (float)a[3] - (float)d[3];
        __builtin_nontemporal_store(s0 * scale, q + 0);
        __builtin_nontemporal_store(s1 * scale, q + 1);
        __builtin_nontemporal_store(s2 * scale, q + 2);
        __builtin_nontemporal_store(s3 * scale, q + 3);
        if (xtra) {
            s8 += (float)*(pa + 4) - (float)*(pd + 4);
            __builtin_nontemporal_store(s8 * scale, q + 4);
        }
        pa += TSTR; pd += TSTR; q += W_OUT;
    }
}

extern "C" void kernel_launch(void* const* d_in, const int* in_sizes, int n_in,
                              void* d_out, int out_size, void* d_ws, size_t ws_size,
                              hipStream_t stream) {
    const float* x = (const float*)d_in[0];
    float* out     = (float*)d_out;
    _Float16* ws   = (_Float16*)d_ws;

    const int B = 32;
    const size_t perBatchT = (size_t)H_IN * TSTR * sizeof(_Float16);  // ~2.32 MB

    int G = (int)(ws_size / perBatchT);
    if (G > B) G = B;
    if (G < 1) G = 1;

    for (int b0 = 0; b0 < B; b0 += G) {
        const int g = (B - b0 < G) ? (B - b0) : G;

        hslide_kernel<<<g * H_IN, 256, 0, stream>>>(
            x + (size_t)b0 * H_IN * W_IN, ws);

        dim3 vgrid(2, NBANDS, g);
        vslide_kernel<<<vgrid, 128, 0, stream>>>(
            ws, out + (size_t)b0 * H_OUT * W_OUT);
    }
}